// Round 1
// baseline (560.922 us; speedup 1.0000x reference)
//
#include <hip/hip_runtime.h>
#include <math.h>

// Problem constants (match reference)
#define BATCH  256
#define TLEN   512
#define NIN    128
#define NHID   128

__device__ __forceinline__ float fsig(float x) {
    return 1.0f / (1.0f + __expf(-x));
}
__device__ __forceinline__ float ftanh(float x) {
    // tanh(x) = 2*sigmoid(2x) - 1
    return 2.0f / (1.0f + __expf(-2.0f * x)) - 1.0f;
}

// One 64-lane wave per batch. Lane owns h indices {lane, lane+64} and
// v = [h | x_t] indices {lane, 64+lane, 128+lane, 192+lane}.
__global__ __launch_bounds__(64, 1) void qlstm_kernel(
    const float* __restrict__ x,       // (B, T, 128)
    const float* __restrict__ W_in,    // (4, 256)
    const float* __restrict__ b_in,    // (4,)
    const float* __restrict__ W_out,   // (128, 4)
    const float* __restrict__ b_out,   // (128,)
    const float* __restrict__ thetas,  // (4, 4)  [gate layer g][wire q]
    float* __restrict__ out)           // hs (B,T,128) ++ h_t (B,128) ++ c_t (B,128)
{
    const int b    = blockIdx.x;
    const int lane = threadIdx.x;

    // ---- preload weights (loop-invariant) ----
    float wh0[4], wh1[4], wx0[4], wx1[4];
#pragma unroll
    for (int q = 0; q < 4; ++q) {
        wh0[q] = W_in[q * 256 + lane];
        wh1[q] = W_in[q * 256 + 64 + lane];
        wx0[q] = W_in[q * 256 + 128 + lane];
        wx1[q] = W_in[q * 256 + 192 + lane];
    }
    float bin[4];
#pragma unroll
    for (int q = 0; q < 4; ++q) bin[q] = b_in[q];

    float th[4][4];
#pragma unroll
    for (int g = 0; g < 4; ++g)
#pragma unroll
        for (int q = 0; q < 4; ++q) th[g][q] = thetas[g * 4 + q];

    float wo0[4], wo1[4];
#pragma unroll
    for (int q = 0; q < 4; ++q) {
        wo0[q] = W_out[lane * 4 + q];
        wo1[q] = W_out[(lane + 64) * 4 + q];
    }
    const float bo0 = b_out[lane];
    const float bo1 = b_out[lane + 64];

    // ---- recurrent state ----
    float h0 = 0.0f, h1 = 0.0f, c0 = 0.0f, c1 = 0.0f;

    const float* xrow = x + (size_t)b * TLEN * NIN;
    float*       orow = out + (size_t)b * TLEN * NHID;

    // prefetch x for t=0
    float xa = xrow[lane];
    float xb = xrow[64 + lane];

    for (int t = 0; t < TLEN; ++t) {
        // prefetch next step's x (independent of the recurrent chain)
        const int tn = (t + 1 < TLEN) ? (t + 1) : (TLEN - 1);
        const float xa_n = xrow[tn * NIN + lane];
        const float xb_n = xrow[tn * NIN + 64 + lane];

        // y[q] = sum_j v[j] * W_in[q,j] + b_in[q],  v = [h | x_t]
        float p0 = h0 * wh0[0] + h1 * wh1[0] + xa * wx0[0] + xb * wx1[0];
        float p1 = h0 * wh0[1] + h1 * wh1[1] + xa * wx0[1] + xb * wx1[1];
        float p2 = h0 * wh0[2] + h1 * wh1[2] + xa * wx0[2] + xb * wx1[2];
        float p3 = h0 * wh0[3] + h1 * wh1[3] + xa * wx0[3] + xb * wx1[3];

        // all-lanes butterfly reduce (every lane ends with the full sum)
#pragma unroll
        for (int off = 32; off >= 1; off >>= 1) {
            p0 += __shfl_xor(p0, off, 64);
            p1 += __shfl_xor(p1, off, 64);
            p2 += __shfl_xor(p2, off, 64);
            p3 += __shfl_xor(p3, off, 64);
        }
        const float y0 = p0 + bin[0];
        const float y1 = p1 + bin[1];
        const float y2 = p2 + bin[2];
        const float y3 = p3 + bin[3];

        // quantum circuit, closed form:
        // m[g,0]=c1c2c3, m[g,1]=c0c1, m[g,2]=c0c1c2, m[g,3]=c0c1c2c3
        float m[4][4];
#pragma unroll
        for (int g = 0; g < 4; ++g) {
            const float cc0 = __cosf(y0 + th[g][0]);
            const float cc1 = __cosf(y1 + th[g][1]);
            const float cc2 = __cosf(y2 + th[g][2]);
            const float cc3 = __cosf(y3 + th[g][3]);
            const float c12 = cc1 * cc2;
            m[g][0] = c12 * cc3;
            m[g][1] = cc0 * cc1;
            m[g][2] = cc0 * c12;
            m[g][3] = m[g][2] * cc3;
        }

        // proj[g,h] = sum_q m[g,q] * W_out[h,q] + b_out[h]
        float pr0[4], pr1[4];
#pragma unroll
        for (int g = 0; g < 4; ++g) {
            pr0[g] = bo0 + m[g][0] * wo0[0] + m[g][1] * wo0[1] +
                            m[g][2] * wo0[2] + m[g][3] * wo0[3];
            pr1[g] = bo1 + m[g][0] * wo1[0] + m[g][1] * wo1[1] +
                            m[g][2] * wo1[2] + m[g][3] * wo1[3];
        }

        // LSTM cell
        {
            const float f = fsig(pr0[0]);
            const float i = fsig(pr0[1]);
            const float g = ftanh(pr0[2]);
            const float o = fsig(pr0[3]);
            c0 = f * c0 + i * g;
            h0 = o * ftanh(c0);
        }
        {
            const float f = fsig(pr1[0]);
            const float i = fsig(pr1[1]);
            const float g = ftanh(pr1[2]);
            const float o = fsig(pr1[3]);
            c1 = f * c1 + i * g;
            h1 = o * ftanh(c1);
        }

        orow[t * NHID + lane]      = h0;
        orow[t * NHID + 64 + lane] = h1;

        xa = xa_n;
        xb = xb_n;
    }

    // final h_t, c_t
    float* ht = out + (size_t)BATCH * TLEN * NHID;
    float* ct = ht + (size_t)BATCH * NHID;
    ht[b * NHID + lane]      = h0;
    ht[b * NHID + 64 + lane] = h1;
    ct[b * NHID + lane]      = c0;
    ct[b * NHID + 64 + lane] = c1;
}

extern "C" void kernel_launch(void* const* d_in, const int* in_sizes, int n_in,
                              void* d_out, int out_size, void* d_ws, size_t ws_size,
                              hipStream_t stream) {
    const float* x      = (const float*)d_in[0];
    const float* W_in   = (const float*)d_in[1];
    const float* b_in   = (const float*)d_in[2];
    const float* W_out  = (const float*)d_in[3];
    const float* b_out  = (const float*)d_in[4];
    const float* thetas = (const float*)d_in[5];
    float* out = (float*)d_out;

    qlstm_kernel<<<dim3(BATCH), dim3(64), 0, stream>>>(
        x, W_in, b_in, W_out, b_out, thetas, out);
}

// Round 2
// 473.589 us; speedup vs baseline: 1.1844x; 1.1844x over previous
//
#include <hip/hip_runtime.h>
#include <math.h>

// Problem constants (match reference)
#define BATCH  256
#define TLEN   512
#define NIN    128
#define NHID   128

#define INV2PI 0.15915494309189535f   // 1/(2*pi): v_cos_f32 takes revolutions
#define NL2E  -1.4426950408889634f    // -log2(e)   (sigmoid gates)
#define N2L2E -2.8853900817779268f    // -2*log2(e) (tanh gates)

// Wave64 sum-reduction via DPP (VALU latency, no LDS path), result broadcast
// to all lanes through readlane(63) -> SGPR. Canonical GCN sequence:
// row_shr:1,2,4,8 then row_bcast:15, row_bcast:31 accumulates the full sum
// into lane 63. bound_ctrl=true zero-fills invalid sources.
__device__ __forceinline__ float wave_sum_bcast(float x) {
    int v = __float_as_int(x);
#define RSTEP(ctrl)                                                          \
    do {                                                                     \
        int t_ = __builtin_amdgcn_update_dpp(0, v, (ctrl), 0xf, 0xf, true);  \
        v = __float_as_int(__int_as_float(v) + __int_as_float(t_));          \
    } while (0)
    RSTEP(0x111);  // row_shr:1
    RSTEP(0x112);  // row_shr:2
    RSTEP(0x114);  // row_shr:4
    RSTEP(0x118);  // row_shr:8   -> lane 15 of each row has row sum
    RSTEP(0x142);  // row_bcast:15
    RSTEP(0x143);  // row_bcast:31 -> lane 63 has full sum
#undef RSTEP
    return __int_as_float(__builtin_amdgcn_readlane(v, 63));
}

// One 64-lane wave per batch. Lane owns h indices {lane, lane+64} and
// v = [h | x_t] indices {lane, 64+lane, 128+lane, 192+lane}.
__global__ __launch_bounds__(64, 1) void qlstm_kernel(
    const float* __restrict__ x,       // (B, T, 128)
    const float* __restrict__ W_in,    // (4, 256)
    const float* __restrict__ b_in,    // (4,)
    const float* __restrict__ W_out,   // (128, 4)
    const float* __restrict__ b_out,   // (128,)
    const float* __restrict__ thetas,  // (4, 4)  [gate layer g][wire q]
    float* __restrict__ out)           // hs (B,T,128) ++ h_t (B,128) ++ c_t (B,128)
{
    const int b    = blockIdx.x;
    const int lane = threadIdx.x;

    // ---- preload weights (loop-invariant, all off the critical path) ----
    float wh0[4], wh1[4], wx0[4], wx1[4];
#pragma unroll
    for (int q = 0; q < 4; ++q) {
        wh0[q] = W_in[q * 256 + lane];
        wh1[q] = W_in[q * 256 + 64 + lane];
        wx0[q] = W_in[q * 256 + 128 + lane];
        wx1[q] = W_in[q * 256 + 192 + lane];
    }

    // theta table with b_in and the 1/(2pi) revolution factor folded in:
    // cos(y_q + b_q + th[g][q]) == v_cos( fma(p_q, INV2PI, th2[g][q]) )
    // where p_q is the raw (bias-free) dot product.
    float th2[4][4];
#pragma unroll
    for (int g = 0; g < 4; ++g)
#pragma unroll
        for (int q = 0; q < 4; ++q)
            th2[g][q] = (thetas[g * 4 + q] + b_in[q]) * INV2PI;

    // W_out/b_out pre-scaled per gate by -log2e (sigmoid) / -2log2e (tanh)
    // so each activation is exp2 + add + rcp with no leading multiply.
    const float gsc0 = NL2E, gsc1 = NL2E, gsc2 = N2L2E, gsc3 = NL2E;
    float wos0[4][4], wos1[4][4], bos0[4], bos1[4];
    {
        float w0[4], w1[4];
#pragma unroll
        for (int q = 0; q < 4; ++q) {
            w0[q] = W_out[lane * 4 + q];
            w1[q] = W_out[(lane + 64) * 4 + q];
        }
        const float bo0 = b_out[lane];
        const float bo1 = b_out[lane + 64];
        const float gs[4] = {gsc0, gsc1, gsc2, gsc3};
#pragma unroll
        for (int g = 0; g < 4; ++g) {
            bos0[g] = gs[g] * bo0;
            bos1[g] = gs[g] * bo1;
#pragma unroll
            for (int q = 0; q < 4; ++q) {
                wos0[g][q] = gs[g] * w0[q];
                wos1[g][q] = gs[g] * w1[q];
            }
        }
    }

    // ---- recurrent state ----
    float h0 = 0.0f, h1 = 0.0f, c0 = 0.0f, c1 = 0.0f;

    const float* xrow = x + (size_t)b * TLEN * NIN;
    float*       orow = out + (size_t)b * TLEN * NHID;

    // prefetch x for t=0
    float xa = xrow[lane];
    float xb = xrow[64 + lane];

    for (int t = 0; t < TLEN; ++t) {
        // prefetch next step's x (independent of the recurrent chain)
        const int tn = (t + 1 < TLEN) ? (t + 1) : (TLEN - 1);
        const float xa_n = xrow[tn * NIN + lane];
        const float xb_n = xrow[tn * NIN + 64 + lane];

        // p[q] = sum_j v[j] * W_in[q,j],  v = [h | x_t]  (bias folded into th2)
        float p0 = h0 * wh0[0] + h1 * wh1[0] + xa * wx0[0] + xb * wx1[0];
        float p1 = h0 * wh0[1] + h1 * wh1[1] + xa * wx0[1] + xb * wx1[1];
        float p2 = h0 * wh0[2] + h1 * wh1[2] + xa * wx0[2] + xb * wx1[2];
        float p3 = h0 * wh0[3] + h1 * wh1[3] + xa * wx0[3] + xb * wx1[3];

        // DPP reduce + uniform broadcast (no LDS path)
        const float y0 = wave_sum_bcast(p0);
        const float y1 = wave_sum_bcast(p1);
        const float y2 = wave_sum_bcast(p2);
        const float y3 = wave_sum_bcast(p3);

        // quantum circuit, closed form:
        // m[g,0]=c1c2c3, m[g,1]=c0c1, m[g,2]=c0c1c2, m[g,3]=c0c1c2c3
        float m[4][4];
#pragma unroll
        for (int g = 0; g < 4; ++g) {
            const float cc0 = __builtin_amdgcn_cosf(__builtin_fmaf(y0, INV2PI, th2[g][0]));
            const float cc1 = __builtin_amdgcn_cosf(__builtin_fmaf(y1, INV2PI, th2[g][1]));
            const float cc2 = __builtin_amdgcn_cosf(__builtin_fmaf(y2, INV2PI, th2[g][2]));
            const float cc3 = __builtin_amdgcn_cosf(__builtin_fmaf(y3, INV2PI, th2[g][3]));
            const float c12 = cc1 * cc2;
            m[g][0] = c12 * cc3;
            m[g][1] = cc0 * cc1;
            m[g][2] = cc0 * c12;
            m[g][3] = m[g][2] * cc3;
        }

        // pre-scaled projections: prS[g] = gs[g]*(b_out + sum_q m[g,q]*W_out)
        float pr0[4], pr1[4];
#pragma unroll
        for (int g = 0; g < 4; ++g) {
            pr0[g] = bos0[g] + m[g][0] * wos0[g][0] + m[g][1] * wos0[g][1] +
                               m[g][2] * wos0[g][2] + m[g][3] * wos0[g][3];
            pr1[g] = bos1[g] + m[g][0] * wos1[g][0] + m[g][1] * wos1[g][1] +
                               m[g][2] * wos1[g][2] + m[g][3] * wos1[g][3];
        }

        // LSTM cell: sigmoid(x) = rcp(1 + exp2(-x*log2e)); scale pre-folded.
        {
            const float f = __builtin_amdgcn_rcpf(1.0f + __builtin_amdgcn_exp2f(pr0[0]));
            const float i = __builtin_amdgcn_rcpf(1.0f + __builtin_amdgcn_exp2f(pr0[1]));
            const float sg = __builtin_amdgcn_rcpf(1.0f + __builtin_amdgcn_exp2f(pr0[2]));
            const float o = __builtin_amdgcn_rcpf(1.0f + __builtin_amdgcn_exp2f(pr0[3]));
            const float g = __builtin_fmaf(2.0f, sg, -1.0f);
            c0 = f * c0 + i * g;
            const float st = __builtin_amdgcn_rcpf(1.0f + __builtin_amdgcn_exp2f(c0 * N2L2E));
            h0 = o * __builtin_fmaf(2.0f, st, -1.0f);
        }
        {
            const float f = __builtin_amdgcn_rcpf(1.0f + __builtin_amdgcn_exp2f(pr1[0]));
            const float i = __builtin_amdgcn_rcpf(1.0f + __builtin_amdgcn_exp2f(pr1[1]));
            const float sg = __builtin_amdgcn_rcpf(1.0f + __builtin_amdgcn_exp2f(pr1[2]));
            const float o = __builtin_amdgcn_rcpf(1.0f + __builtin_amdgcn_exp2f(pr1[3]));
            const float g = __builtin_fmaf(2.0f, sg, -1.0f);
            c1 = f * c1 + i * g;
            const float st = __builtin_amdgcn_rcpf(1.0f + __builtin_amdgcn_exp2f(c1 * N2L2E));
            h1 = o * __builtin_fmaf(2.0f, st, -1.0f);
        }

        orow[t * NHID + lane]      = h0;
        orow[t * NHID + 64 + lane] = h1;

        xa = xa_n;
        xb = xb_n;
    }

    // final h_t, c_t
    float* ht = out + (size_t)BATCH * TLEN * NHID;
    float* ct = ht + (size_t)BATCH * NHID;
    ht[b * NHID + lane]      = h0;
    ht[b * NHID + 64 + lane] = h1;
    ct[b * NHID + lane]      = c0;
    ct[b * NHID + 64 + lane] = c1;
}

extern "C" void kernel_launch(void* const* d_in, const int* in_sizes, int n_in,
                              void* d_out, int out_size, void* d_ws, size_t ws_size,
                              hipStream_t stream) {
    const float* x      = (const float*)d_in[0];
    const float* W_in   = (const float*)d_in[1];
    const float* b_in   = (const float*)d_in[2];
    const float* W_out  = (const float*)d_in[3];
    const float* b_out  = (const float*)d_in[4];
    const float* thetas = (const float*)d_in[5];
    float* out = (float*)d_out;

    qlstm_kernel<<<dim3(BATCH), dim3(64), 0, stream>>>(
        x, W_in, b_in, W_out, b_out, thetas, out);
}

// Round 4
// 346.843 us; speedup vs baseline: 1.6172x; 1.3654x over previous
//
#include <hip/hip_runtime.h>
#include <math.h>

// Problem constants (match reference)
#define BATCH  256
#define TLEN   512
#define NIN    128
#define NHID   128

#define DEPTH  8                      // x-prefetch pipeline depth (steps)

#define INV2PI 0.15915494309189535f   // 1/(2*pi): v_cos_f32 takes revolutions
#define NL2E  -1.4426950408889634f    // -log2(e)   (sigmoid gates)
#define N2L2E -2.8853900817779268f    // -2*log2(e) (tanh gates)

// Wave64 sum-reduction via DPP (VALU latency, no LDS path), result broadcast
// to all lanes through readlane(63) -> SGPR.
__device__ __forceinline__ float wave_sum_bcast(float x) {
    int v = __float_as_int(x);
#define RSTEP(ctrl)                                                          \
    do {                                                                     \
        int t_ = __builtin_amdgcn_update_dpp(0, v, (ctrl), 0xf, 0xf, true);  \
        v = __float_as_int(__int_as_float(v) + __int_as_float(t_));          \
    } while (0)
    RSTEP(0x111);  // row_shr:1
    RSTEP(0x112);  // row_shr:2
    RSTEP(0x114);  // row_shr:4
    RSTEP(0x118);  // row_shr:8   -> lane 15 of each row has row sum
    RSTEP(0x142);  // row_bcast:15
    RSTEP(0x143);  // row_bcast:31 -> lane 63 has full sum
#undef RSTEP
    return __int_as_float(__builtin_amdgcn_readlane(v, 63));
}

// One 64-lane wave per batch. Lane owns h indices {lane, lane+64} and
// v = [h | x_t] indices {lane, 64+lane, 128+lane, 192+lane}.
__global__ __launch_bounds__(64, 1) void qlstm_kernel(
    const float* __restrict__ x,       // (B, T, 128)
    const float* __restrict__ W_in,    // (4, 256)
    const float* __restrict__ b_in,    // (4,)
    const float* __restrict__ W_out,   // (128, 4)
    const float* __restrict__ b_out,   // (128,)
    const float* __restrict__ thetas,  // (4, 4)  [gate layer g][wire q]
    float* __restrict__ out)           // hs (B,T,128) ++ h_t (B,128) ++ c_t (B,128)
{
    const int b    = blockIdx.x;
    const int lane = threadIdx.x;

    // ---- preload weights (loop-invariant, off the critical path) ----
    float wh0[4], wh1[4], wx0[4], wx1[4];
#pragma unroll
    for (int q = 0; q < 4; ++q) {
        wh0[q] = W_in[q * 256 + lane];
        wh1[q] = W_in[q * 256 + 64 + lane];
        wx0[q] = W_in[q * 256 + 128 + lane];
        wx1[q] = W_in[q * 256 + 192 + lane];
    }

    // theta table with b_in and the 1/(2pi) revolution factor folded in:
    // cos(y_q + b_q + th[g][q]) == v_cos( fma(p_q, INV2PI, th2[g][q]) )
    float th2[4][4];
#pragma unroll
    for (int g = 0; g < 4; ++g)
#pragma unroll
        for (int q = 0; q < 4; ++q)
            th2[g][q] = (thetas[g * 4 + q] + b_in[q]) * INV2PI;

    // W_out/b_out pre-scaled per gate by -log2e (sigmoid) / -2log2e (tanh)
    float wos0[4][4], wos1[4][4], bos0[4], bos1[4];
    {
        float w0[4], w1[4];
#pragma unroll
        for (int q = 0; q < 4; ++q) {
            w0[q] = W_out[lane * 4 + q];
            w1[q] = W_out[(lane + 64) * 4 + q];
        }
        const float bo0 = b_out[lane];
        const float bo1 = b_out[lane + 64];
        const float gs[4] = {NL2E, NL2E, N2L2E, NL2E};
#pragma unroll
        for (int g = 0; g < 4; ++g) {
            bos0[g] = gs[g] * bo0;
            bos1[g] = gs[g] * bo1;
#pragma unroll
            for (int q = 0; q < 4; ++q) {
                wos0[g][q] = gs[g] * w0[q];
                wos1[g][q] = gs[g] * w1[q];
            }
        }
    }

    // ---- recurrent state ----
    float h0 = 0.0f, h1 = 0.0f, c0 = 0.0f, c1 = 0.0f;

    const float* xrow = x + (size_t)b * TLEN * NIN;
    float*       orow = out + (size_t)b * TLEN * NHID;

    // ---- x prefetch pipeline: DEPTH steps in flight (static indices only) ----
    float xA[DEPTH], xB[DEPTH];
#pragma unroll
    for (int d = 0; d < DEPTH; ++d) {
        xA[d] = xrow[d * NIN + lane];
        xB[d] = xrow[d * NIN + 64 + lane];
    }

    for (int tb = 0; tb < TLEN; tb += DEPTH) {
#pragma unroll
        for (int d = 0; d < DEPTH; ++d) {
            const int t = tb + d;

            const float xa = xA[d];
            const float xb = xB[d];

            // issue the load for step t+DEPTH into this slot (consumed in
            // DEPTH steps -> ~8 x step-time of latency hiding). Clamped
            // address for the tail (harmless re-read, branch-free).
            const int tn = (t + DEPTH < TLEN) ? (t + DEPTH) : (TLEN - 1);
            xA[d] = xrow[tn * NIN + lane];
            xB[d] = xrow[tn * NIN + 64 + lane];

            // p[q] = sum_j v[j] * W_in[q,j],  v = [h | x_t]
            float p0 = h0 * wh0[0] + h1 * wh1[0] + xa * wx0[0] + xb * wx1[0];
            float p1 = h0 * wh0[1] + h1 * wh1[1] + xa * wx0[1] + xb * wx1[1];
            float p2 = h0 * wh0[2] + h1 * wh1[2] + xa * wx0[2] + xb * wx1[2];
            float p3 = h0 * wh0[3] + h1 * wh1[3] + xa * wx0[3] + xb * wx1[3];

            // DPP reduce + uniform broadcast (no LDS path)
            const float y0 = wave_sum_bcast(p0);
            const float y1 = wave_sum_bcast(p1);
            const float y2 = wave_sum_bcast(p2);
            const float y3 = wave_sum_bcast(p3);

            // quantum circuit, closed form:
            // m[g,0]=c1c2c3, m[g,1]=c0c1, m[g,2]=c0c1c2, m[g,3]=c0c1c2c3
            float m[4][4];
#pragma unroll
            for (int g = 0; g < 4; ++g) {
                const float cc0 = __builtin_amdgcn_cosf(__builtin_fmaf(y0, INV2PI, th2[g][0]));
                const float cc1 = __builtin_amdgcn_cosf(__builtin_fmaf(y1, INV2PI, th2[g][1]));
                const float cc2 = __builtin_amdgcn_cosf(__builtin_fmaf(y2, INV2PI, th2[g][2]));
                const float cc3 = __builtin_amdgcn_cosf(__builtin_fmaf(y3, INV2PI, th2[g][3]));
                const float c12 = cc1 * cc2;
                m[g][0] = c12 * cc3;
                m[g][1] = cc0 * cc1;
                m[g][2] = cc0 * c12;
                m[g][3] = m[g][2] * cc3;
            }

            // pre-scaled projections
            float pr0[4], pr1[4];
#pragma unroll
            for (int g = 0; g < 4; ++g) {
                pr0[g] = bos0[g] + m[g][0] * wos0[g][0] + m[g][1] * wos0[g][1] +
                                   m[g][2] * wos0[g][2] + m[g][3] * wos0[g][3];
                pr1[g] = bos1[g] + m[g][0] * wos1[g][0] + m[g][1] * wos1[g][1] +
                                   m[g][2] * wos1[g][2] + m[g][3] * wos1[g][3];
            }

            // LSTM cell: sigmoid(x) = rcp(1 + exp2(-x*log2e)); scale pre-folded.
            {
                const float f  = __builtin_amdgcn_rcpf(1.0f + __builtin_amdgcn_exp2f(pr0[0]));
                const float i  = __builtin_amdgcn_rcpf(1.0f + __builtin_amdgcn_exp2f(pr0[1]));
                const float sg = __builtin_amdgcn_rcpf(1.0f + __builtin_amdgcn_exp2f(pr0[2]));
                const float o  = __builtin_amdgcn_rcpf(1.0f + __builtin_amdgcn_exp2f(pr0[3]));
                const float g  = __builtin_fmaf(2.0f, sg, -1.0f);
                c0 = f * c0 + i * g;
                const float st = __builtin_amdgcn_rcpf(1.0f + __builtin_amdgcn_exp2f(c0 * N2L2E));
                h0 = o * __builtin_fmaf(2.0f, st, -1.0f);
            }
            {
                const float f  = __builtin_amdgcn_rcpf(1.0f + __builtin_amdgcn_exp2f(pr1[0]));
                const float i  = __builtin_amdgcn_rcpf(1.0f + __builtin_amdgcn_exp2f(pr1[1]));
                const float sg = __builtin_amdgcn_rcpf(1.0f + __builtin_amdgcn_exp2f(pr1[2]));
                const float o  = __builtin_amdgcn_rcpf(1.0f + __builtin_amdgcn_exp2f(pr1[3]));
                const float g  = __builtin_fmaf(2.0f, sg, -1.0f);
                c1 = f * c1 + i * g;
                const float st = __builtin_amdgcn_rcpf(1.0f + __builtin_amdgcn_exp2f(c1 * N2L2E));
                h1 = o * __builtin_fmaf(2.0f, st, -1.0f);
            }

            orow[t * NHID + lane]      = h0;
            orow[t * NHID + 64 + lane] = h1;
        }
    }

    // final h_t, c_t
    float* ht = out + (size_t)BATCH * TLEN * NHID;
    float* ct = ht + (size_t)BATCH * NHID;
    ht[b * NHID + lane]      = h0;
    ht[b * NHID + 64 + lane] = h1;
    ct[b * NHID + lane]      = c0;
    ct[b * NHID + 64 + lane] = c1;
}

extern "C" void kernel_launch(void* const* d_in, const int* in_sizes, int n_in,
                              void* d_out, int out_size, void* d_ws, size_t ws_size,
                              hipStream_t stream) {
    const float* x      = (const float*)d_in[0];
    const float* W_in   = (const float*)d_in[1];
    const float* b_in   = (const float*)d_in[2];
    const float* W_out  = (const float*)d_in[3];
    const float* b_out  = (const float*)d_in[4];
    const float* thetas = (const float*)d_in[5];
    float* out = (float*)d_out;

    qlstm_kernel<<<dim3(BATCH), dim3(64), 0, stream>>>(
        x, W_in, b_in, W_out, b_out, thetas, out);
}

// Round 7
// 334.944 us; speedup vs baseline: 1.6747x; 1.0355x over previous
//
#include <hip/hip_runtime.h>

// Problem constants (match reference)
#define BATCH  256
#define TLEN   512
#define NIN    128
#define NHID   128

#define INV2PI 0.15915494309189535f   // 1/(2*pi): v_cos_f32 takes revolutions
#define NL2E  -1.4426950408889634f    // -log2(e)   (sigmoid gates)
#define N2L2E -2.8853900817779268f    // -2*log2(e) (tanh gates)

// Wave64 sum-reduction via DPP (VALU path only), result broadcast via
// readlane(63) -> SGPR. Proven in rounds 2-4.
__device__ __forceinline__ float wave_sum_bcast(float x) {
    int v = __float_as_int(x);
#define RSTEP(ctrl)                                                          \
    { int t_ = __builtin_amdgcn_update_dpp(0, v, (ctrl), 0xf, 0xf, true);    \
      v = __float_as_int(__int_as_float(v) + __int_as_float(t_)); }
    RSTEP(0x111)  // row_shr:1
    RSTEP(0x112)  // row_shr:2
    RSTEP(0x114)  // row_shr:4
    RSTEP(0x118)  // row_shr:8
    RSTEP(0x142)  // row_bcast:15
    RSTEP(0x143)  // row_bcast:31 -> lane 63 has full sum
#undef RSTEP
    return __int_as_float(__builtin_amdgcn_readlane(v, 63));
}

// ---------------------------------------------------------------------------
// Pass 1: Y[bt][q] = (x_bt . Wx_q + b_in[q]) * INV2PI  stored in out[bt*128+q]
// (slot is consumed at step t of pass 2 before the h-row overwrites it).
// One wave per (b,t) row; massively parallel, throughput-bound.
// ---------------------------------------------------------------------------
__global__ __launch_bounds__(256) void y_pre_kernel(
    const float* __restrict__ x, const float* __restrict__ W_in,
    const float* __restrict__ b_in, float* __restrict__ out)
{
    const int lane = threadIdx.x & 63;
    const int wv   = threadIdx.x >> 6;
    const int bt   = (blockIdx.x << 2) + wv;          // = b*TLEN + t

    const float xa = x[(size_t)bt * NIN + lane];
    const float xb = x[(size_t)bt * NIN + 64 + lane];

    float yq[4];
#pragma unroll
    for (int q = 0; q < 4; ++q) {
        const float p = xa * W_in[q * 256 + 128 + lane]
                      + xb * W_in[q * 256 + 192 + lane];
        yq[q] = (wave_sum_bcast(p) + b_in[q]) * INV2PI;
    }
    if (lane < 4) {
        const float v = (lane == 0) ? yq[0] : (lane == 1) ? yq[1]
                      : (lane == 2) ? yq[2] : yq[3];
        out[(size_t)bt * NHID + lane] = v;
    }
}

// ---------------------------------------------------------------------------
// Pass 2: recurrent kernel. 1 block (256 thr = 4 waves) per batch.
// Phase A (wave = one qubit q): y_q reduce + 4 cosines -> LDS (16 floats).
// Phase B (lane = one h-index, 2x duplicated): m, proj, gates, c/h update.
// Issue-cadence limited chain now split over all 4 SIMDs of the CU.
// ---------------------------------------------------------------------------
__global__ __launch_bounds__(256, 1) void qlstm_rec_kernel(
    const float* __restrict__ W_in,    // (4, 256)
    const float* __restrict__ thetas,  // (4, 4)  [gate g][wire q]
    const float* __restrict__ W_out,   // (128, 4)
    const float* __restrict__ b_out,   // (128,)
    float* __restrict__ out)           // hs (B,T,128) ++ h_t ++ c_t
{
    const int b    = blockIdx.x;
    const int lane = threadIdx.x & 63;
    const int wv   = threadIdx.x >> 6;        // wave id = qubit q in phase A

    __shared__ float h_sh[128];
    __shared__ __align__(16) float cs_sh[16]; // [q][g]

    // ---- phase-A weights (own qubit q = wv); INV2PI folded into Wh ----
    const float whA = W_in[wv * 256 + lane]      * INV2PI;
    const float whB = W_in[wv * 256 + 64 + lane] * INV2PI;
    float th2[4];
#pragma unroll
    for (int g = 0; g < 4; ++g) th2[g] = thetas[g * 4 + wv] * INV2PI;

    // ---- phase-B weights (own h-index; gate scale pre-folded) ----
    const int hidx = wv * 32 + (lane & 31);
    const float gsc[4] = {NL2E, NL2E, N2L2E, NL2E};
    float wos[4][4], bos[4];
#pragma unroll
    for (int g = 0; g < 4; ++g) {
        bos[g] = gsc[g] * b_out[hidx];
#pragma unroll
        for (int q = 0; q < 4; ++q) wos[g][q] = gsc[g] * W_out[hidx * 4 + q];
    }

    float c = 0.0f, h_st = 0.0f;
    if (threadIdx.x < 128) h_sh[threadIdx.x] = 0.0f;
    __syncthreads();

    float* orow = out + (size_t)b * TLEN * NHID;

    // Y prefetch (4 steps deep; wave-uniform scalar per wave)
    float Yp[4];
#pragma unroll
    for (int d = 0; d < 4; ++d) Yp[d] = orow[d * NHID + wv];

    for (int tb = 0; tb < TLEN; tb += 4) {
#pragma unroll
        for (int d = 0; d < 4; ++d) {
            const int t = tb + d;

            // ---- body-top VMEM (far from the barriers' vmcnt drain) ----
            if (t > 0) orow[(t - 1) * NHID + hidx] = h_st;  // delayed h store
            const float Ysc = Yp[d];
            const int   tn  = (t + 4 < TLEN) ? t + 4 : TLEN - 1;
            Yp[d] = orow[tn * NHID + wv];

            // ---- phase A: own qubit's y + 4 cosines ----
            const float ha = h_sh[lane];
            const float hb = h_sh[64 + lane];
            const float y  = wave_sum_bcast(ha * whA + hb * whB);
            float cg0 = __builtin_amdgcn_cosf(y + (Ysc + th2[0]));
            float cg1 = __builtin_amdgcn_cosf(y + (Ysc + th2[1]));
            float cg2 = __builtin_amdgcn_cosf(y + (Ysc + th2[2]));
            float cg3 = __builtin_amdgcn_cosf(y + (Ysc + th2[3]));
            if (lane == 0)
                *(float4*)&cs_sh[wv * 4] = make_float4(cg0, cg1, cg2, cg3);
            __syncthreads();

            // ---- phase B: one h-index per lane ----
            const float4 q0 = *(const float4*)&cs_sh[0];   // c_{q=0}[g=0..3]
            const float4 q1 = *(const float4*)&cs_sh[4];
            const float4 q2 = *(const float4*)&cs_sh[8];
            const float4 q3 = *(const float4*)&cs_sh[12];

            float pr[4];
#define GATE(G, C0, C1, C2, C3)                                              \
            {                                                                \
                const float a_  = (C1) * (C2);                               \
                const float m0_ = a_ * (C3);                                 \
                const float m1_ = (C0) * (C1);                               \
                const float m2_ = (C0) * a_;                                 \
                const float m3_ = m2_ * (C3);                                \
                pr[G] = bos[G] + m0_ * wos[G][0] + m1_ * wos[G][1]           \
                               + m2_ * wos[G][2] + m3_ * wos[G][3];          \
            }
            GATE(0, q0.x, q1.x, q2.x, q3.x)
            GATE(1, q0.y, q1.y, q2.y, q3.y)
            GATE(2, q0.z, q1.z, q2.z, q3.z)
            GATE(3, q0.w, q1.w, q2.w, q3.w)
#undef GATE

            const float ef = __builtin_amdgcn_exp2f(pr[0]);
            const float ei = __builtin_amdgcn_exp2f(pr[1]);
            const float eg = __builtin_amdgcn_exp2f(pr[2]);
            const float eo = __builtin_amdgcn_exp2f(pr[3]);
            const float f  = __builtin_amdgcn_rcpf(1.0f + ef);
            const float i  = __builtin_amdgcn_rcpf(1.0f + ei);
            const float sg = __builtin_amdgcn_rcpf(1.0f + eg);
            const float o  = __builtin_amdgcn_rcpf(1.0f + eo);
            const float g2 = __builtin_fmaf(2.0f, sg, -1.0f);
            c = f * c + i * g2;
            const float ec = __builtin_amdgcn_exp2f(c * N2L2E);
            const float st = __builtin_amdgcn_rcpf(1.0f + ec);
            const float h  = o * __builtin_fmaf(2.0f, st, -1.0f);

            h_st = h;
            h_sh[hidx] = h;
            __syncthreads();
        }
    }

    // tail: last h row + final h_t, c_t
    orow[(TLEN - 1) * NHID + hidx] = h_st;
    float* ht = out + (size_t)BATCH * TLEN * NHID;
    float* ct = ht + (size_t)BATCH * NHID;
    ht[b * NHID + hidx] = h_st;
    ct[b * NHID + hidx] = c;
}

extern "C" void kernel_launch(void* const* d_in, const int* in_sizes, int n_in,
                              void* d_out, int out_size, void* d_ws, size_t ws_size,
                              hipStream_t stream) {
    const float* x      = (const float*)d_in[0];
    const float* W_in   = (const float*)d_in[1];
    const float* b_in   = (const float*)d_in[2];
    const float* W_out  = (const float*)d_in[3];
    const float* b_out  = (const float*)d_in[4];
    const float* thetas = (const float*)d_in[5];
    float* out = (float*)d_out;

    // Pass 1: Y pre-compute (one wave per (b,t); 4 waves per block)
    y_pre_kernel<<<dim3((BATCH * TLEN) / 4), dim3(256), 0, stream>>>(
        x, W_in, b_in, out);

    // Pass 2: recurrent scan (one block per batch, 4 waves on 4 SIMDs)
    qlstm_rec_kernel<<<dim3(BATCH), dim3(256), 0, stream>>>(
        W_in, thetas, W_out, b_out, out);
}

// Round 8
// 332.739 us; speedup vs baseline: 1.6858x; 1.0066x over previous
//
#include <hip/hip_runtime.h>

// Problem constants (match reference)
#define BATCH  256
#define TLEN   512
#define NIN    128
#define NHID   128

#define INV2PI 0.15915494309189535f   // 1/(2*pi): v_cos_f32 takes revolutions
#define NL2E  -1.4426950408889634f    // -log2(e)   (sigmoid gates)
#define N2L2E -2.8853900817779268f    // -2*log2(e) (tanh gates)

// Wave64 sum-reduction via DPP (VALU path only), result broadcast via
// readlane(63) -> SGPR. Proven in rounds 2-7.
__device__ __forceinline__ float wave_sum_bcast(float x) {
    int v = __float_as_int(x);
#define RSTEP(ctrl)                                                          \
    { int t_ = __builtin_amdgcn_update_dpp(0, v, (ctrl), 0xf, 0xf, true);    \
      v = __float_as_int(__int_as_float(v) + __int_as_float(t_)); }
    RSTEP(0x111)  // row_shr:1
    RSTEP(0x112)  // row_shr:2
    RSTEP(0x114)  // row_shr:4
    RSTEP(0x118)  // row_shr:8
    RSTEP(0x142)  // row_bcast:15
    RSTEP(0x143)  // row_bcast:31 -> lane 63 has full sum
#undef RSTEP
    return __int_as_float(__builtin_amdgcn_readlane(v, 63));
}

// Barrier that drains ONLY the LDS queue (lgkmcnt), not vmcnt: the delayed
// global h-store and the Y prefetch loads stay in flight across it.
__device__ __forceinline__ void barrier_lds() {
    asm volatile("s_waitcnt lgkmcnt(0)\n\ts_barrier" ::: "memory");
}

// ---------------------------------------------------------------------------
// Pass 1: Y[bt][q] = (x_bt . Wx_q + b_in[q]) * INV2PI  stored in out[bt*128+q]
// (slot is consumed at step t of pass 2 before the h-row overwrites it).
// ---------------------------------------------------------------------------
__global__ __launch_bounds__(256) void y_pre_kernel(
    const float* __restrict__ x, const float* __restrict__ W_in,
    const float* __restrict__ b_in, float* __restrict__ out)
{
    const int lane = threadIdx.x & 63;
    const int wv   = threadIdx.x >> 6;
    const int bt   = (blockIdx.x << 2) + wv;          // = b*TLEN + t

    const float xa = x[(size_t)bt * NIN + lane];
    const float xb = x[(size_t)bt * NIN + 64 + lane];

    float yq[4];
#pragma unroll
    for (int q = 0; q < 4; ++q) {
        const float p = xa * W_in[q * 256 + 128 + lane]
                      + xb * W_in[q * 256 + 192 + lane];
        yq[q] = (wave_sum_bcast(p) + b_in[q]) * INV2PI;
    }
    if (lane < 4) {
        const float v = (lane == 0) ? yq[0] : (lane == 1) ? yq[1]
                      : (lane == 2) ? yq[2] : yq[3];
        out[(size_t)bt * NHID + lane] = v;
    }
}

// ---------------------------------------------------------------------------
// Pass 2: recurrent kernel. 1 block (4 waves) per batch; h/c REPLICATED in
// registers in every wave (each lane owns h{lane, 64+lane}).
// Phase A: wave wv computes its own qubit's y (2 FMA + DPP reduce, no LDS
//          read) + 4 cosines -> double-buffered cs_sh. ONE lgkm-only barrier.
// Phase B: all waves redundantly compute the full gate/c/h update from the
//          16 broadcast cosines; waves 0/1 store the h row (delayed 1 step).
// ---------------------------------------------------------------------------
__global__ __launch_bounds__(256, 1) void qlstm_rec_kernel(
    const float* __restrict__ W_in,    // (4, 256)
    const float* __restrict__ thetas,  // (4, 4)  [gate g][wire q]
    const float* __restrict__ W_out,   // (128, 4)
    const float* __restrict__ b_out,   // (128,)
    float* __restrict__ out)           // hs (B,T,128) ++ h_t ++ c_t
{
    const int b    = blockIdx.x;
    const int lane = threadIdx.x & 63;
    const int wv   = threadIdx.x >> 6;        // wave id = qubit q in phase A

    __shared__ __align__(16) float cs_sh[2][16];   // [t&1][q*4+g]

    // ---- phase-A weights (own qubit q = wv); INV2PI folded into Wh ----
    const float whA = W_in[wv * 256 + lane]      * INV2PI;
    const float whB = W_in[wv * 256 + 64 + lane] * INV2PI;
    float th2[4];
#pragma unroll
    for (int g = 0; g < 4; ++g) th2[g] = thetas[g * 4 + wv] * INV2PI;

    // ---- phase-B weights for BOTH owned h-indices (gate scale folded) ----
    const float gsc[4] = {NL2E, NL2E, N2L2E, NL2E};
    float wos0[4][4], wos1[4][4], bos0[4], bos1[4];
#pragma unroll
    for (int g = 0; g < 4; ++g) {
        bos0[g] = gsc[g] * b_out[lane];
        bos1[g] = gsc[g] * b_out[64 + lane];
#pragma unroll
        for (int q = 0; q < 4; ++q) {
            wos0[g][q] = gsc[g] * W_out[lane * 4 + q];
            wos1[g][q] = gsc[g] * W_out[(64 + lane) * 4 + q];
        }
    }

    float h0 = 0.0f, h1 = 0.0f, c0 = 0.0f, c1 = 0.0f;
    float* orow = out + (size_t)b * TLEN * NHID;

    // Y prefetch (4 steps deep; wave-uniform scalar per wave)
    float Yp[4];
#pragma unroll
    for (int d = 0; d < 4; ++d) Yp[d] = orow[d * NHID + wv];

    for (int tb = 0; tb < TLEN; tb += 4) {
#pragma unroll
        for (int d = 0; d < 4; ++d) {
            const int t = tb + d;

            // ---- delayed h(t-1) store: issued at step top, never waited on
            if (t > 0) {
                if (wv == 0)      orow[(t - 1) * NHID + lane]      = h0;
                else if (wv == 1) orow[(t - 1) * NHID + 64 + lane] = h1;
            }

            // ---- phase A: own qubit's y from REGISTERS + 4 cosines ----
            const float p    = h0 * whA + h1 * whB;
            const float base = wave_sum_bcast(p) + Yp[d];
            const float cg0 = __builtin_amdgcn_cosf(base + th2[0]);
            const float cg1 = __builtin_amdgcn_cosf(base + th2[1]);
            const float cg2 = __builtin_amdgcn_cosf(base + th2[2]);
            const float cg3 = __builtin_amdgcn_cosf(base + th2[3]);
            if (lane == 0)
                *(float4*)&cs_sh[d & 1][wv * 4] = make_float4(cg0, cg1, cg2, cg3);

            // Y refill for step t+4 (uses this slot's next life)
            const int tn = (t + 4 < TLEN) ? t + 4 : TLEN - 1;
            Yp[d] = orow[tn * NHID + wv];

            barrier_lds();   // lgkmcnt-only; double-buffered cs -> 1/step

            // ---- phase B (replicated in all waves): gates + c/h update ----
            const float4 q0 = *(const float4*)&cs_sh[d & 1][0];
            const float4 q1 = *(const float4*)&cs_sh[d & 1][4];
            const float4 q2 = *(const float4*)&cs_sh[d & 1][8];
            const float4 q3 = *(const float4*)&cs_sh[d & 1][12];

            float pr0[4], pr1[4];
#define GATE(G, C0, C1, C2, C3)                                              \
            {                                                                \
                const float a_  = (C1) * (C2);                               \
                const float m0_ = a_ * (C3);                                 \
                const float m1_ = (C0) * (C1);                               \
                const float m2_ = (C0) * a_;                                 \
                const float m3_ = m2_ * (C3);                                \
                pr0[G] = bos0[G] + m0_ * wos0[G][0] + m1_ * wos0[G][1]       \
                                 + m2_ * wos0[G][2] + m3_ * wos0[G][3];      \
                pr1[G] = bos1[G] + m0_ * wos1[G][0] + m1_ * wos1[G][1]       \
                                 + m2_ * wos1[G][2] + m3_ * wos1[G][3];      \
            }
            GATE(0, q0.x, q1.x, q2.x, q3.x)
            GATE(1, q0.y, q1.y, q2.y, q3.y)
            GATE(2, q0.z, q1.z, q2.z, q3.z)
            GATE(3, q0.w, q1.w, q2.w, q3.w)
#undef GATE

            {
                const float f  = __builtin_amdgcn_rcpf(1.0f + __builtin_amdgcn_exp2f(pr0[0]));
                const float i  = __builtin_amdgcn_rcpf(1.0f + __builtin_amdgcn_exp2f(pr0[1]));
                const float sg = __builtin_amdgcn_rcpf(1.0f + __builtin_amdgcn_exp2f(pr0[2]));
                const float o  = __builtin_amdgcn_rcpf(1.0f + __builtin_amdgcn_exp2f(pr0[3]));
                const float g2 = __builtin_fmaf(2.0f, sg, -1.0f);
                c0 = f * c0 + i * g2;
                const float st = __builtin_amdgcn_rcpf(1.0f + __builtin_amdgcn_exp2f(c0 * N2L2E));
                h0 = o * __builtin_fmaf(2.0f, st, -1.0f);
            }
            {
                const float f  = __builtin_amdgcn_rcpf(1.0f + __builtin_amdgcn_exp2f(pr1[0]));
                const float i  = __builtin_amdgcn_rcpf(1.0f + __builtin_amdgcn_exp2f(pr1[1]));
                const float sg = __builtin_amdgcn_rcpf(1.0f + __builtin_amdgcn_exp2f(pr1[2]));
                const float o  = __builtin_amdgcn_rcpf(1.0f + __builtin_amdgcn_exp2f(pr1[3]));
                const float g2 = __builtin_fmaf(2.0f, sg, -1.0f);
                c1 = f * c1 + i * g2;
                const float st = __builtin_amdgcn_rcpf(1.0f + __builtin_amdgcn_exp2f(c1 * N2L2E));
                h1 = o * __builtin_fmaf(2.0f, st, -1.0f);
            }
            // no second barrier: cs double-buffer removes the WAR hazard
        }
    }

    // tail: last h row + final h_t, c_t (state replicated; waves 0/1 write)
    float* ht = out + (size_t)BATCH * TLEN * NHID;
    float* ct = ht + (size_t)BATCH * NHID;
    if (wv == 0) {
        orow[(TLEN - 1) * NHID + lane] = h0;
        ht[b * NHID + lane] = h0;
        ct[b * NHID + lane] = c0;
    } else if (wv == 1) {
        orow[(TLEN - 1) * NHID + 64 + lane] = h1;
        ht[b * NHID + 64 + lane] = h1;
        ct[b * NHID + 64 + lane] = c1;
    }
}

extern "C" void kernel_launch(void* const* d_in, const int* in_sizes, int n_in,
                              void* d_out, int out_size, void* d_ws, size_t ws_size,
                              hipStream_t stream) {
    const float* x      = (const float*)d_in[0];
    const float* W_in   = (const float*)d_in[1];
    const float* b_in   = (const float*)d_in[2];
    const float* W_out  = (const float*)d_in[3];
    const float* b_out  = (const float*)d_in[4];
    const float* thetas = (const float*)d_in[5];
    float* out = (float*)d_out;

    // Pass 1: Y pre-compute (one wave per (b,t); 4 waves per block)
    y_pre_kernel<<<dim3((BATCH * TLEN) / 4), dim3(256), 0, stream>>>(
        x, W_in, b_in, out);

    // Pass 2: recurrent scan (one block per batch, 4 waves on 4 SIMDs)
    qlstm_rec_kernel<<<dim3(BATCH), dim3(256), 0, stream>>>(
        W_in, thetas, W_out, b_out, out);
}